// Round 15
// baseline (105.081 us; speedup 1.0000x reference)
//
#include <hip/hip_runtime.h>

// B=16, L=2048, V=64.
// Algebraic reduction (e is one-hot):
//   E[d] = exp(v_emb[d]); S[t] = prefix_sum(E)[t]
//   F[b,c,s] = sum_{k<=s} E[s-k] * Wq[idx[b,k], c]            (causal Toeplitz GEMM)
//   P[b,c,s] = exp(F[b,c,s] / S[s])                           (softmax w/o max; scores tiny)
//   out[b,t,v] = Wv00 * (sum_{s<=t, idx[b,s]==v} P[b,c_t,s]) / (sum_{s<=t} P[b,c_t,s]),  c_t = idx[b,t]
//
// R31: R30 on-prediction (101.3; u32-paired A-gather -2.5us). The B-path is
// now the larger LDS item: 8 consecutive-u32 ds_read_b32 per wave/K-step,
// split only by the per-lane parity of off_=s_>>1. Generalize GL0/GL1 to
// FOUR phase-shifted copies GL[r][i]=GLv(i+r), r=0..3 -> base (s_-r) is a
// multiple of 4 -> each 8-u16 B fragment = 2 aligned ds_read_b64 (4 per
// frag-pair vs 8 b32). Steady LDS instr/wave/K-step: 17 -> 13 (-24%).
// GL LDS 8.8->17.9KB (total 38.8KB, still 4 blocks/CU; VGPR << 128).
// Boundary audit: reads span u16 idx [96, 2174]; E[2047]@GL0[2174] is the
// exact top; low zeros [96,127-r) staged. Everything else byte-identical.
// Predicted k1 -2.5-3.5us, total 101.3 -> 97.5-99.5.

#define LSEQ 2048
#define NB 16
#define NV 64
#define NC 32             // 32 chunks of 64
#define NBLK 1024

typedef __attribute__((ext_vector_type(8))) short bf16x8;
typedef __attribute__((ext_vector_type(4))) float f32x4;

__device__ __forceinline__ unsigned short f2bf(float f) {   // RNE float->bf16
  unsigned int u = __float_as_uint(f);
  return (unsigned short)((u + 0x7FFFu + ((u >> 16) & 1u)) >> 16);
}

// =====================================================================
// K1: setup (WqP/ro/E/S in LDS) + causal-Toeplitz MFMA GEMM, 1 32-col
// tile per block; CU-balanced tile permutation; (mh,kh) wave split;
// column-paired u32 A-gather; 4-phase GL with b64 B-loads.
// =====================================================================
__global__ __launch_bounds__(256, 4) void k_gemm(
    const int* __restrict__ idx, const float* __restrict__ Wq,
    const float* __restrict__ v_emb, float* __restrict__ P) {
  struct SMem {
    unsigned int WqP[64 * 33];    // paired bf16 cols: [row][p]=(c0|c1<<16), 8448B
    unsigned short ro[2048];      // ro[i] = idx[b,2047-i]*33 (4096B)
    alignas(16) unsigned short GL[4][2240];  // GL[r][i] = GLv(i+r), 17920B
    float red[16][64];
    float red2[16][64];
    float Spart[32];              // S[n0..n0+32) for this block's tile
    float swsum[4];
  };
  __shared__ SMem sm;

  const int bid = blockIdx.x;     // [0, 1024)
  const int tid = threadIdx.x;
  const int w = tid >> 6;
  const int lane = tid & 63;

  // CU-balanced permutation: CU = bid mod 256, slot v = bid>>8.
  // b = u&15, t = u>>4; bn = {t, 31-t, 32+t, 63-t}[v].
  // Per-CU work = (t+1)+(32-t)+(33+t)+(64-t) = 130 k-units, constant.
  const int u = bid & 255;
  const int v = bid >> 8;
  const int b = u & 15;
  const int t = u >> 4;
  const int bn = (v == 0) ? t : (v == 1) ? (31 - t) : (v == 2) ? (32 + t)
                                                              : (63 - t);
  const int n0 = bn * 32;
  const int quad = lane >> 4;
  const int lm = lane & 15;
  const int mh = w & 1;                    // M-half: cols mh*32 .. mh*32+31
  const int kh = w >> 1;                   // k-half 0 / 1

  // ---------------- setup: Wq -> LDS paired bf16, ro, E/S -------------
  {
    // WqP staging: 2048 u32, 8 per thread; (c0,c1) = (p+(p&16), +16)
#pragma unroll
    for (int uu = 0; uu < 8; ++uu) {
      const int e = tid * 8 + uu;          // [0,2048); row const per thread
      const int row = e >> 5;
      const int p = e & 31;
      const int c0 = p + (p & 16);
      sm.WqP[row * 33 + p] =
          (unsigned int)f2bf(Wq[row * 64 + c0]) |
          ((unsigned int)f2bf(Wq[row * 64 + c0 + 16]) << 16);
    }
#pragma unroll
    for (int j = 0; j < 8; ++j) {
      const int tt = tid * 8 + j;
      sm.ro[2047 - tt] = (unsigned short)(idx[b * LSEQ + tt] * 33);
    }
    float ev[8], ps8[8];
    float tot = 0.f;
    const int t0 = tid * 8;
#pragma unroll
    for (int j = 0; j < 8; ++j) {
      const float e = expf(v_emb[t0 + j]);
      tot += e; ev[j] = e; ps8[j] = tot;
    }
    float ws = tot;                        // wave-inclusive scan of thread sums
#pragma unroll
    for (int d = 1; d < 64; d <<= 1) {
      float up = __shfl_up(ws, d);
      if (lane >= d) ws += up;
    }
    if (lane == 63) sm.swsum[w] = ws;
    __syncthreads();
    float wbase = 0.f;
#pragma unroll
    for (int k = 0; k < 4; ++k) if (k < w) wbase += sm.swsum[k];
    const float base = wbase + (ws - tot); // exclusive base for this thread
#pragma unroll
    for (int j = 0; j < 8; ++j) {
      const int d = t0 + j;
      const float Sv = base + ps8[j];
      if ((unsigned)(d - n0) < 32u) sm.Spart[d - n0] = Sv;
      const unsigned short bv = f2bf(ev[j]);
      sm.GL[0][d + 127] = bv;              // GL[r][i] = GLv(i+r) = E[i+r-127]
      sm.GL[1][d + 126] = bv;
      sm.GL[2][d + 125] = bv;
      sm.GL[3][d + 124] = bv;
    }
    if (tid < 31) sm.GL[0][96 + tid] = 0;  // zero [96,127)
    if (tid < 30) sm.GL[1][96 + tid] = 0;  // zero [96,126)
    if (tid < 29) sm.GL[2][96 + tid] = 0;  // zero [96,125)
    if (tid < 28) sm.GL[3][96 + tid] = 0;  // zero [96,124)
    __syncthreads();                       // all LDS (WqP/ro/GL/Spart) ready
  }

  // ---------------- MFMA GEMM, fully block-local ----------------------
  {
    const int sbase = n0 + lm - 1920;      // B col (s) base for this lane
    const int kstart = 2048 - (n0 + 32);   // multiple of 32
    const int iters = bn + 1;              // total 32-k steps for this tile
    const int pbase = mh * 16 + lm;        // pair index for this lane

    f32x4 acc[2][2];                       // [mt2][ns]
#pragma unroll
    for (int mt = 0; mt < 2; ++mt)
#pragma unroll
      for (int ns = 0; ns < 2; ++ns) acc[mt][ns] = (f32x4){0.f, 0.f, 0.f, 0.f};

    union AF { unsigned short s[8]; bf16x8 v; };
    union BF { unsigned int u[4]; bf16x8 v; };
    AF a[3][2];
    BF bb[3][2];

// A via paired u32 gather (1 ds_read_b32 per row covers both mt cols);
// B via phase-shifted GL: base (s_ - (s_&3)) is 4-aligned -> 2 ds_read_b64
// per fragment, 4 per frag-pair (frag1 at +16: same phase, q_+4/q_+5).
#define LOAD_FRAGS(J_, SL) do {                                             \
    const int k_ = kstart + (kh + 2 * (J_)) * 32;                           \
    const int i0_ = k_ + quad * 8;                                          \
    unsigned short ro_[8];                                                  \
    *(uint4*)ro_ = *(const uint4*)&sm.ro[i0_];                              \
_Pragma("unroll")                                                           \
    for (int j_ = 0; j_ < 8; ++j_) {                                        \
      const unsigned int r_ = sm.WqP[(int)ro_[j_] + pbase];                 \
      a[SL][0].s[j_] = (unsigned short)r_;                                  \
      a[SL][1].s[j_] = (unsigned short)(r_ >> 16);                          \
    }                                                                       \
    const int s_ = sbase + k_ + quad * 8;                                   \
    const uint2* gq_ = (const uint2*)&sm.GL[s_ & 3][0];                     \
    const int q_ = s_ >> 2;                                                 \
    const uint2 x0_ = gq_[q_ + 0], x1_ = gq_[q_ + 1];                       \
    const uint2 x2_ = gq_[q_ + 4], x3_ = gq_[q_ + 5];                       \
    bb[SL][0].u[0] = x0_.x; bb[SL][0].u[1] = x0_.y;                         \
    bb[SL][0].u[2] = x1_.x; bb[SL][0].u[3] = x1_.y;                         \
    bb[SL][1].u[0] = x2_.x; bb[SL][1].u[1] = x2_.y;                         \
    bb[SL][1].u[2] = x3_.x; bb[SL][1].u[3] = x3_.y;                         \
  } while (0)

#define MFMA8(SL) do {                                                      \
    acc[0][0] = __builtin_amdgcn_mfma_f32_16x16x32_bf16(a[SL][0].v, bb[SL][0].v, acc[0][0], 0, 0, 0); \
    acc[0][1] = __builtin_amdgcn_mfma_f32_16x16x32_bf16(a[SL][0].v, bb[SL][1].v, acc[0][1], 0, 0, 0); \
    acc[1][0] = __builtin_amdgcn_mfma_f32_16x16x32_bf16(a[SL][1].v, bb[SL][0].v, acc[1][0], 0, 0, 0); \
    acc[1][1] = __builtin_amdgcn_mfma_f32_16x16x32_bf16(a[SL][1].v, bb[SL][1].v, acc[1][1], 0, 0, 0); \
  } while (0)

    const int J = (iters > kh) ? ((iters - kh + 1) >> 1) : 0;  // wave-iters
    if (J > 0) {
      LOAD_FRAGS(0, 0);
      if (J > 1) LOAD_FRAGS(1, 1);
      int j = 0;
      while (true) {
        if (j + 2 < J) LOAD_FRAGS(j + 2, 2);
        MFMA8(0);
        if (++j >= J) break;
        if (j + 2 < J) LOAD_FRAGS(j + 2, 0);
        MFMA8(1);
        if (++j >= J) break;
        if (j + 2 < J) LOAD_FRAGS(j + 2, 1);
        MFMA8(2);
        if (++j >= J) break;
      }
    }
#undef LOAD_FRAGS
#undef MFMA8

    // reduce k-half 1 into k-half 0 via LDS (red keyed by mh; 16 rows/wave)
    if (kh == 1) {
      float (*rd)[64] = mh ? sm.red2 : sm.red;
#pragma unroll
      for (int mt = 0; mt < 2; ++mt)
#pragma unroll
        for (int ns = 0; ns < 2; ++ns)
#pragma unroll
          for (int r = 0; r < 4; ++r)
            rd[(mt * 2 + ns) * 4 + r][lane] = acc[mt][ns][r];
    }
    __syncthreads();
    if (kh == 0) {
      float (*rd)[64] = mh ? sm.red2 : sm.red;
#pragma unroll
      for (int mt = 0; mt < 2; ++mt)
#pragma unroll
        for (int ns = 0; ns < 2; ++ns)
#pragma unroll
          for (int r = 0; r < 4; ++r)
            acc[mt][ns][r] += rd[(mt * 2 + ns) * 4 + r][lane];

      // epilogue: C/D layout col(s)=lm, row(c)=quad*4+r; NORMAL stores
#pragma unroll
      for (int ns = 0; ns < 2; ++ns) {
        const float sinv = 1.0f / sm.Spart[ns * 16 + lm];
#pragma unroll
        for (int mt = 0; mt < 2; ++mt) {
#pragma unroll
          for (int r = 0; r < 4; ++r) {
            const int c = mh * 32 + mt * 16 + quad * 4 + r;
            P[((size_t)(b * 64 + c)) * LSEQ + n0 + ns * 16 + lm] =
                __expf(acc[mt][ns][r] * sinv);
          }
        }
      }
    }
  }
}

// =====================================================================
// K2: chunk-hists + scan + fence-free emission, 1 (b,c) per block.
// P visible via the kernel boundary; reads served from L2/IC.
// =====================================================================
__global__ __launch_bounds__(256, 8) void k_scanemit(
    const int* __restrict__ idx, const float* __restrict__ P,
    const float* __restrict__ Wv, float* __restrict__ out) {
  __shared__ float Hs[NC][65];
  __shared__ float pl[4][64];
  __shared__ unsigned long long mk[4][64];

  const int bc = blockIdx.x;      // [0, 1024)
  const int b = bc >> 6;
  const int c = bc & 63;
  const int w = threadIdx.x >> 6;
  const int lane = threadIdx.x & 63;
  const int tid = threadIdx.x;

  const float* __restrict__ prow = P + (size_t)bc * LSEQ;
  const int* __restrict__ irow = idx + b * LSEQ;

  float p[8]; int ii[8];
#pragma unroll
  for (int r = 0; r < 8; ++r) {           // 16 independent coalesced loads
    const int ch = w * 8 + r;
    p[r] = prow[ch * 64 + lane];
    ii[r] = irow[ch * 64 + lane];
  }
  for (int i = tid; i < NC * 65; i += 256) ((float*)Hs)[i] = 0.f;
  __syncthreads();
#pragma unroll
  for (int r = 0; r < 8; ++r) atomicAdd(&Hs[w * 8 + r][ii[r]], p[r]);
  __syncthreads();

  // exclusive scan across chunks, per bin: 2 bins per pass (lane halves)
  const int hhalf = lane >> 5, l32 = lane & 31;
#pragma unroll
  for (int r = 0; r < 8; ++r) {
    const int v = w * 16 + r * 2 + hhalf;
    const float h = Hs[l32][v];
    float x = h;
#pragma unroll
    for (int d = 1; d < 32; d <<= 1) {
      float up = __shfl_up(x, d, 32);
      if (l32 >= d) x += up;
    }
    Hs[l32][v] = x - h;                   // exclusive
  }
  __syncthreads();

  const float wv = Wv[0];
#pragma unroll
  for (int r = 0; r < 8; ++r) {
    const int ch = w * 8 + r;
    unsigned long long em = __ballot(ii[r] == c);   // emission points
    if (em == 0ull) continue;                       // wave-uniform skip
    // per-chunk setup (wave-synchronous LDS, no fences):
    pl[w][lane] = p[r];                             // stage p
    mk[w][lane] = 0ull;
    atomicOr(&mk[w][ii[r]], 1ull << lane);          // bin <- source lanes
    float ps = p[r];                                // within-chunk prefix
#pragma unroll
    for (int d = 1; d < 64; d <<= 1) {
      float up = __shfl_up(ps, d);
      if (lane >= d) ps += up;
    }
    const float hbase = Hs[ch][lane];
    float zex = hbase;                              // Z_excl = sum_v Hs
#pragma unroll
    for (int d = 1; d < 64; d <<= 1) zex += __shfl_xor(zex, d);
    const unsigned long long myMask = mk[w][lane];
    while (em) {
      const int srel = __builtin_ctzll(em);
      em &= em - 1;
      unsigned long long mm = myMask &
          ((srel == 63) ? ~0ull : ((1ull << (srel + 1)) - 1ull));
      float B = hbase;                              // bin value at this t
      while (mm) { const int l = __builtin_ctzll(mm); mm &= mm - 1; B += pl[w][l]; }
      const float z = zex + __shfl(ps, srel);       // denominator
      out[((size_t)(b * LSEQ + ch * 64 + srel)) * 64 + lane] = wv * B / z;
    }
  }
}

extern "C" void kernel_launch(void* const* d_in, const int* in_sizes, int n_in,
                              void* d_out, int out_size, void* d_ws, size_t ws_size,
                              hipStream_t stream) {
  const int* idx     = (const int*)d_in[0];     // [16, 2048]
  const float* Wq    = (const float*)d_in[1];   // [64, 64]
  const float* Wv    = (const float*)d_in[2];   // [64, 64] (only [0,0] used)
  const float* v_emb = (const float*)d_in[3];   // [2048, 1]
  float* out = (float*)d_out;                   // [16, 2048, 64] fp32

  // workspace: [2048 f32 pad] | P[1024*2048] f32
  float* P = (float*)d_ws + LSEQ;

  k_gemm<<<dim3(NBLK), dim3(256), 0, stream>>>(idx, Wq, v_emb, P);
  k_scanemit<<<dim3(NBLK), dim3(256), 0, stream>>>(idx, P, Wv, out);
}

// Round 16
// 102.372 us; speedup vs baseline: 1.0265x; 1.0265x over previous
//
#include <hip/hip_runtime.h>

// B=16, L=2048, V=64.
// Algebraic reduction (e is one-hot):
//   E[d] = exp(v_emb[d]); S[t] = prefix_sum(E)[t]
//   F[b,c,s] = sum_{k<=s} E[s-k] * Wq[idx[b,k], c]            (causal Toeplitz GEMM)
//   P[b,c,s] = exp(F[b,c,s] / S[s])                           (softmax w/o max; scores tiny)
//   out[b,t,v] = Wv00 * (sum_{s<=t, idx[b,s]==v} P[b,c_t,s]) / (sum_{s<=t} P[b,c_t,s]),  c_t = idx[b,t]
//
// R32: R31 regressed (105.1 vs R30's 101.3). Address audit found why:
// GL[4][2240] stride = 4480B = 1120 dwords, 1120 mod 32 = 0 -> all four
// phase buffers start at BANK 0, so each 4-lane group (consecutive s_,
// phases 0-3, same q_) hits the same 2-bank pair -> every B ds_read_b64 was
// a 4-way conflict (1.58x, m136). One-line fix: pad to GL[4][2248] ->
// stride 4496B = 1124 dwords, mod 32 = 4 -> GL[r] starts at bank 4r ->
// the phase group lands on 4 distinct bank pairs, conflict-free, keeping
// the -24% LDS-instruction win. 4496%8=0 (b64-aligned); boundary audit
// unchanged (max idx 2174 < 2248). Everything else identical to R31.
// Predicted total 96-100 (must beat 101.3); else revert to R30.

#define LSEQ 2048
#define NB 16
#define NV 64
#define NC 32             // 32 chunks of 64
#define NBLK 1024

typedef __attribute__((ext_vector_type(8))) short bf16x8;
typedef __attribute__((ext_vector_type(4))) float f32x4;

__device__ __forceinline__ unsigned short f2bf(float f) {   // RNE float->bf16
  unsigned int u = __float_as_uint(f);
  return (unsigned short)((u + 0x7FFFu + ((u >> 16) & 1u)) >> 16);
}

// =====================================================================
// K1: setup (WqP/ro/E/S in LDS) + causal-Toeplitz MFMA GEMM, 1 32-col
// tile per block; CU-balanced tile permutation; (mh,kh) wave split;
// column-paired u32 A-gather; 4-phase GL (bank-staggered) b64 B-loads.
// =====================================================================
__global__ __launch_bounds__(256, 4) void k_gemm(
    const int* __restrict__ idx, const float* __restrict__ Wq,
    const float* __restrict__ v_emb, float* __restrict__ P) {
  struct SMem {
    unsigned int WqP[64 * 33];    // paired bf16 cols: [row][p]=(c0|c1<<16), 8448B
    unsigned short ro[2048];      // ro[i] = idx[b,2047-i]*33 (4096B)
    alignas(16) unsigned short GL[4][2248];  // GL[r][i] = GLv(i+r); stride
                                  // 4496B = 1124 dw, mod 32 = 4 -> bank 4r
    float red[16][64];
    float red2[16][64];
    float Spart[32];              // S[n0..n0+32) for this block's tile
    float swsum[4];
  };
  __shared__ SMem sm;

  const int bid = blockIdx.x;     // [0, 1024)
  const int tid = threadIdx.x;
  const int w = tid >> 6;
  const int lane = tid & 63;

  // CU-balanced permutation: CU = bid mod 256, slot v = bid>>8.
  // b = u&15, t = u>>4; bn = {t, 31-t, 32+t, 63-t}[v].
  // Per-CU work = (t+1)+(32-t)+(33+t)+(64-t) = 130 k-units, constant.
  const int u = bid & 255;
  const int v = bid >> 8;
  const int b = u & 15;
  const int t = u >> 4;
  const int bn = (v == 0) ? t : (v == 1) ? (31 - t) : (v == 2) ? (32 + t)
                                                              : (63 - t);
  const int n0 = bn * 32;
  const int quad = lane >> 4;
  const int lm = lane & 15;
  const int mh = w & 1;                    // M-half: cols mh*32 .. mh*32+31
  const int kh = w >> 1;                   // k-half 0 / 1

  // ---------------- setup: Wq -> LDS paired bf16, ro, E/S -------------
  {
    // WqP staging: 2048 u32, 8 per thread; (c0,c1) = (p+(p&16), +16)
#pragma unroll
    for (int uu = 0; uu < 8; ++uu) {
      const int e = tid * 8 + uu;          // [0,2048); row const per thread
      const int row = e >> 5;
      const int p = e & 31;
      const int c0 = p + (p & 16);
      sm.WqP[row * 33 + p] =
          (unsigned int)f2bf(Wq[row * 64 + c0]) |
          ((unsigned int)f2bf(Wq[row * 64 + c0 + 16]) << 16);
    }
#pragma unroll
    for (int j = 0; j < 8; ++j) {
      const int tt = tid * 8 + j;
      sm.ro[2047 - tt] = (unsigned short)(idx[b * LSEQ + tt] * 33);
    }
    float ev[8], ps8[8];
    float tot = 0.f;
    const int t0 = tid * 8;
#pragma unroll
    for (int j = 0; j < 8; ++j) {
      const float e = expf(v_emb[t0 + j]);
      tot += e; ev[j] = e; ps8[j] = tot;
    }
    float ws = tot;                        // wave-inclusive scan of thread sums
#pragma unroll
    for (int d = 1; d < 64; d <<= 1) {
      float up = __shfl_up(ws, d);
      if (lane >= d) ws += up;
    }
    if (lane == 63) sm.swsum[w] = ws;
    __syncthreads();
    float wbase = 0.f;
#pragma unroll
    for (int k = 0; k < 4; ++k) if (k < w) wbase += sm.swsum[k];
    const float base = wbase + (ws - tot); // exclusive base for this thread
#pragma unroll
    for (int j = 0; j < 8; ++j) {
      const int d = t0 + j;
      const float Sv = base + ps8[j];
      if ((unsigned)(d - n0) < 32u) sm.Spart[d - n0] = Sv;
      const unsigned short bv = f2bf(ev[j]);
      sm.GL[0][d + 127] = bv;              // GL[r][i] = GLv(i+r) = E[i+r-127]
      sm.GL[1][d + 126] = bv;
      sm.GL[2][d + 125] = bv;
      sm.GL[3][d + 124] = bv;
    }
    if (tid < 31) sm.GL[0][96 + tid] = 0;  // zero [96,127)
    if (tid < 30) sm.GL[1][96 + tid] = 0;  // zero [96,126)
    if (tid < 29) sm.GL[2][96 + tid] = 0;  // zero [96,125)
    if (tid < 28) sm.GL[3][96 + tid] = 0;  // zero [96,124)
    __syncthreads();                       // all LDS (WqP/ro/GL/Spart) ready
  }

  // ---------------- MFMA GEMM, fully block-local ----------------------
  {
    const int sbase = n0 + lm - 1920;      // B col (s) base for this lane
    const int kstart = 2048 - (n0 + 32);   // multiple of 32
    const int iters = bn + 1;              // total 32-k steps for this tile
    const int pbase = mh * 16 + lm;        // pair index for this lane

    f32x4 acc[2][2];                       // [mt2][ns]
#pragma unroll
    for (int mt = 0; mt < 2; ++mt)
#pragma unroll
      for (int ns = 0; ns < 2; ++ns) acc[mt][ns] = (f32x4){0.f, 0.f, 0.f, 0.f};

    union AF { unsigned short s[8]; bf16x8 v; };
    union BF { unsigned int u[4]; bf16x8 v; };
    AF a[3][2];
    BF bb[3][2];

// A via paired u32 gather (1 ds_read_b32 per row covers both mt cols);
// B via bank-staggered phase-shifted GL: base (s_-(s_&3)) is 4-aligned ->
// 2 ds_read_b64 per fragment, 4 per frag-pair (frag1 at +16: q_+4/q_+5).
#define LOAD_FRAGS(J_, SL) do {                                             \
    const int k_ = kstart + (kh + 2 * (J_)) * 32;                           \
    const int i0_ = k_ + quad * 8;                                          \
    unsigned short ro_[8];                                                  \
    *(uint4*)ro_ = *(const uint4*)&sm.ro[i0_];                              \
_Pragma("unroll")                                                           \
    for (int j_ = 0; j_ < 8; ++j_) {                                        \
      const unsigned int r_ = sm.WqP[(int)ro_[j_] + pbase];                 \
      a[SL][0].s[j_] = (unsigned short)r_;                                  \
      a[SL][1].s[j_] = (unsigned short)(r_ >> 16);                          \
    }                                                                       \
    const int s_ = sbase + k_ + quad * 8;                                   \
    const uint2* gq_ = (const uint2*)&sm.GL[s_ & 3][0];                     \
    const int q_ = s_ >> 2;                                                 \
    const uint2 x0_ = gq_[q_ + 0], x1_ = gq_[q_ + 1];                       \
    const uint2 x2_ = gq_[q_ + 4], x3_ = gq_[q_ + 5];                       \
    bb[SL][0].u[0] = x0_.x; bb[SL][0].u[1] = x0_.y;                         \
    bb[SL][0].u[2] = x1_.x; bb[SL][0].u[3] = x1_.y;                         \
    bb[SL][1].u[0] = x2_.x; bb[SL][1].u[1] = x2_.y;                         \
    bb[SL][1].u[2] = x3_.x; bb[SL][1].u[3] = x3_.y;                         \
  } while (0)

#define MFMA8(SL) do {                                                      \
    acc[0][0] = __builtin_amdgcn_mfma_f32_16x16x32_bf16(a[SL][0].v, bb[SL][0].v, acc[0][0], 0, 0, 0); \
    acc[0][1] = __builtin_amdgcn_mfma_f32_16x16x32_bf16(a[SL][0].v, bb[SL][1].v, acc[0][1], 0, 0, 0); \
    acc[1][0] = __builtin_amdgcn_mfma_f32_16x16x32_bf16(a[SL][1].v, bb[SL][0].v, acc[1][0], 0, 0, 0); \
    acc[1][1] = __builtin_amdgcn_mfma_f32_16x16x32_bf16(a[SL][1].v, bb[SL][1].v, acc[1][1], 0, 0, 0); \
  } while (0)

    const int J = (iters > kh) ? ((iters - kh + 1) >> 1) : 0;  // wave-iters
    if (J > 0) {
      LOAD_FRAGS(0, 0);
      if (J > 1) LOAD_FRAGS(1, 1);
      int j = 0;
      while (true) {
        if (j + 2 < J) LOAD_FRAGS(j + 2, 2);
        MFMA8(0);
        if (++j >= J) break;
        if (j + 2 < J) LOAD_FRAGS(j + 2, 0);
        MFMA8(1);
        if (++j >= J) break;
        if (j + 2 < J) LOAD_FRAGS(j + 2, 1);
        MFMA8(2);
        if (++j >= J) break;
      }
    }
#undef LOAD_FRAGS
#undef MFMA8

    // reduce k-half 1 into k-half 0 via LDS (red keyed by mh; 16 rows/wave)
    if (kh == 1) {
      float (*rd)[64] = mh ? sm.red2 : sm.red;
#pragma unroll
      for (int mt = 0; mt < 2; ++mt)
#pragma unroll
        for (int ns = 0; ns < 2; ++ns)
#pragma unroll
          for (int r = 0; r < 4; ++r)
            rd[(mt * 2 + ns) * 4 + r][lane] = acc[mt][ns][r];
    }
    __syncthreads();
    if (kh == 0) {
      float (*rd)[64] = mh ? sm.red2 : sm.red;
#pragma unroll
      for (int mt = 0; mt < 2; ++mt)
#pragma unroll
        for (int ns = 0; ns < 2; ++ns)
#pragma unroll
          for (int r = 0; r < 4; ++r)
            acc[mt][ns][r] += rd[(mt * 2 + ns) * 4 + r][lane];

      // epilogue: C/D layout col(s)=lm, row(c)=quad*4+r; NORMAL stores
#pragma unroll
      for (int ns = 0; ns < 2; ++ns) {
        const float sinv = 1.0f / sm.Spart[ns * 16 + lm];
#pragma unroll
        for (int mt = 0; mt < 2; ++mt) {
#pragma unroll
          for (int r = 0; r < 4; ++r) {
            const int c = mh * 32 + mt * 16 + quad * 4 + r;
            P[((size_t)(b * 64 + c)) * LSEQ + n0 + ns * 16 + lm] =
                __expf(acc[mt][ns][r] * sinv);
          }
        }
      }
    }
  }
}

// =====================================================================
// K2: chunk-hists + scan + fence-free emission, 1 (b,c) per block.
// P visible via the kernel boundary; reads served from L2/IC.
// =====================================================================
__global__ __launch_bounds__(256, 8) void k_scanemit(
    const int* __restrict__ idx, const float* __restrict__ P,
    const float* __restrict__ Wv, float* __restrict__ out) {
  __shared__ float Hs[NC][65];
  __shared__ float pl[4][64];
  __shared__ unsigned long long mk[4][64];

  const int bc = blockIdx.x;      // [0, 1024)
  const int b = bc >> 6;
  const int c = bc & 63;
  const int w = threadIdx.x >> 6;
  const int lane = threadIdx.x & 63;
  const int tid = threadIdx.x;

  const float* __restrict__ prow = P + (size_t)bc * LSEQ;
  const int* __restrict__ irow = idx + b * LSEQ;

  float p[8]; int ii[8];
#pragma unroll
  for (int r = 0; r < 8; ++r) {           // 16 independent coalesced loads
    const int ch = w * 8 + r;
    p[r] = prow[ch * 64 + lane];
    ii[r] = irow[ch * 64 + lane];
  }
  for (int i = tid; i < NC * 65; i += 256) ((float*)Hs)[i] = 0.f;
  __syncthreads();
#pragma unroll
  for (int r = 0; r < 8; ++r) atomicAdd(&Hs[w * 8 + r][ii[r]], p[r]);
  __syncthreads();

  // exclusive scan across chunks, per bin: 2 bins per pass (lane halves)
  const int hhalf = lane >> 5, l32 = lane & 31;
#pragma unroll
  for (int r = 0; r < 8; ++r) {
    const int v = w * 16 + r * 2 + hhalf;
    const float h = Hs[l32][v];
    float x = h;
#pragma unroll
    for (int d = 1; d < 32; d <<= 1) {
      float up = __shfl_up(x, d, 32);
      if (l32 >= d) x += up;
    }
    Hs[l32][v] = x - h;                   // exclusive
  }
  __syncthreads();

  const float wv = Wv[0];
#pragma unroll
  for (int r = 0; r < 8; ++r) {
    const int ch = w * 8 + r;
    unsigned long long em = __ballot(ii[r] == c);   // emission points
    if (em == 0ull) continue;                       // wave-uniform skip
    // per-chunk setup (wave-synchronous LDS, no fences):
    pl[w][lane] = p[r];                             // stage p
    mk[w][lane] = 0ull;
    atomicOr(&mk[w][ii[r]], 1ull << lane);          // bin <- source lanes
    float ps = p[r];                                // within-chunk prefix
#pragma unroll
    for (int d = 1; d < 64; d <<= 1) {
      float up = __shfl_up(ps, d);
      if (lane >= d) ps += up;
    }
    const float hbase = Hs[ch][lane];
    float zex = hbase;                              // Z_excl = sum_v Hs
#pragma unroll
    for (int d = 1; d < 64; d <<= 1) zex += __shfl_xor(zex, d);
    const unsigned long long myMask = mk[w][lane];
    while (em) {
      const int srel = __builtin_ctzll(em);
      em &= em - 1;
      unsigned long long mm = myMask &
          ((srel == 63) ? ~0ull : ((1ull << (srel + 1)) - 1ull));
      float B = hbase;                              // bin value at this t
      while (mm) { const int l = __builtin_ctzll(mm); mm &= mm - 1; B += pl[w][l]; }
      const float z = zex + __shfl(ps, srel);       // denominator
      out[((size_t)(b * LSEQ + ch * 64 + srel)) * 64 + lane] = wv * B / z;
    }
  }
}

extern "C" void kernel_launch(void* const* d_in, const int* in_sizes, int n_in,
                              void* d_out, int out_size, void* d_ws, size_t ws_size,
                              hipStream_t stream) {
  const int* idx     = (const int*)d_in[0];     // [16, 2048]
  const float* Wq    = (const float*)d_in[1];   // [64, 64]
  const float* Wv    = (const float*)d_in[2];   // [64, 64] (only [0,0] used)
  const float* v_emb = (const float*)d_in[3];   // [2048, 1]
  float* out = (float*)d_out;                   // [16, 2048, 64] fp32

  // workspace: [2048 f32 pad] | P[1024*2048] f32
  float* P = (float*)d_ws + LSEQ;

  k_gemm<<<dim3(NBLK), dim3(256), 0, stream>>>(idx, Wq, v_emb, P);
  k_scanemit<<<dim3(NBLK), dim3(256), 0, stream>>>(idx, P, Wv, out);
}